// Round 2
// baseline (125.197 us; speedup 1.0000x reference)
//
#include <hip/hip_runtime.h>
#include <math.h>

// RWKV WKV forward, chunked-scan formulation, latency-optimized.
// State triple (aa, bb, pp) represents A = e^pp * aa, B = e^pp * bb.
// Chunk of length L maps state linearly -> associative combine over chunks.

#define NEG_INF (-1e38f)
#define GSZ 4   // software-pipeline group size (timesteps prefetched ahead)

__device__ __forceinline__ void wkv_step(float& aa, float& bb, float& pp,
                                         float wc, float kt, float vt) {
    float ww = wc + pp;
    float p  = fmaxf(ww, kt);
    float d  = ww - kt;
    float e  = __expf(-fabsf(d));          // exp(min-max), single transcendental
    float e1 = (d >= 0.f) ? 1.f : e;
    float e2 = (d >= 0.f) ? e   : 1.f;
    aa = e1 * aa + e2 * vt;
    bb = e1 * bb + e2;
    pp = p;
}

__device__ __forceinline__ float wkv_ostep(float aa, float bb, float pp,
                                           float uc, float kt, float vt) {
    float ww = uc + kt;
    float d  = pp - ww;
    float e  = __expf(-fabsf(d));
    float e1 = (d >= 0.f) ? 1.f : e;
    float e2 = (d >= 0.f) ? e   : 1.f;
    return __fdividef(e1 * aa + e2 * vt, e1 * bb + e2);
}

// Pass 1: per-(b,chunk) local state. One block per (b,j); 384 threads; each
// thread owns 2 adjacent channels (float2). Block streams contiguous memory.
__global__ __launch_bounds__(384, 6)
void wkv_chunk_state(const float* __restrict__ w,
                     const float* __restrict__ kg,
                     const float* __restrict__ vg,
                     float* __restrict__ sa,
                     float* __restrict__ sb,
                     float* __restrict__ sp,
                     int B, int T, int C, int L, int NC) {
    const int bj  = blockIdx.x;
    const int b   = bj / NC;
    const int j   = bj - b * NC;
    const int tid = threadIdx.x;           // 0 .. C/2-1
    const int C2  = C >> 1;

    const float2* kp = (const float2*)(kg + ((size_t)b * T + (size_t)j * L) * C) + tid;
    const float2* vp = (const float2*)(vg + ((size_t)b * T + (size_t)j * L) * C) + tid;
    const float2  wc = ((const float2*)w)[tid];

    float aa0 = 0.f, bb0 = 0.f, pp0 = NEG_INF;
    float aa1 = 0.f, bb1 = 0.f, pp1 = NEG_INF;

    float2 kb[GSZ], vb[GSZ];
    #pragma unroll
    for (int g = 0; g < GSZ; ++g) { kb[g] = kp[g * C2]; vb[g] = vp[g * C2]; }

    for (int t0 = 0; t0 < L - GSZ; t0 += GSZ) {
        float2 kn[GSZ], vn[GSZ];
        #pragma unroll
        for (int g = 0; g < GSZ; ++g) {    // prefetch next group
            kn[g] = kp[(t0 + GSZ + g) * C2];
            vn[g] = vp[(t0 + GSZ + g) * C2];
        }
        #pragma unroll
        for (int g = 0; g < GSZ; ++g) {    // compute current group
            wkv_step(aa0, bb0, pp0, wc.x, kb[g].x, vb[g].x);
            wkv_step(aa1, bb1, pp1, wc.y, kb[g].y, vb[g].y);
        }
        #pragma unroll
        for (int g = 0; g < GSZ; ++g) { kb[g] = kn[g]; vb[g] = vn[g]; }
    }
    #pragma unroll
    for (int g = 0; g < GSZ; ++g) {        // epilogue group
        wkv_step(aa0, bb0, pp0, wc.x, kb[g].x, vb[g].x);
        wkv_step(aa1, bb1, pp1, wc.y, kb[g].y, vb[g].y);
    }

    const int base = j * (B * C) + b * C + 2 * tid;
    *(float2*)(sa + base) = make_float2(aa0, aa1);
    *(float2*)(sb + base) = make_float2(bb0, bb1);
    *(float2*)(sp + base) = make_float2(pp0, pp1);
}

// Pass 2: sequential prefix over chunks per channel; overwrite summaries
// in place with the carry-in state for each chunk.
__global__ void wkv_prefix(const float* __restrict__ w,
                           float* __restrict__ sa,
                           float* __restrict__ sb,
                           float* __restrict__ sp,
                           int B, int C, int L, int NC) {
    int bc = blockIdx.x * blockDim.x + threadIdx.x;
    int BC = B * C;
    if (bc >= BC) return;
    int c = bc % C;
    float wL = w[c] * (float)L;

    float aa = 0.f, bb = 0.f, pp = NEG_INF;
    for (int j = 0; j < NC; ++j) {
        int idx = j * BC + bc;
        float la = sa[idx];
        float lb = sb[idx];
        float lp = sp[idx];
        sa[idx] = aa; sb[idx] = bb; sp[idx] = pp;   // carry-in for chunk j
        float ppd = pp + wL;
        float p   = fmaxf(ppd, lp);
        float e1  = __expf(ppd - p);
        float e2  = __expf(lp - p);
        aa = e1 * aa + e2 * la;
        bb = e1 * bb + e2 * lb;
        pp = p;
    }
}

// Pass 3: recompute within chunk from carry-in, emit y.
__global__ __launch_bounds__(384, 6)
void wkv_out(const float* __restrict__ w,
             const float* __restrict__ u,
             const float* __restrict__ kg,
             const float* __restrict__ vg,
             const float* __restrict__ sa,
             const float* __restrict__ sb,
             const float* __restrict__ sp,
             float* __restrict__ y,
             int B, int T, int C, int L, int NC) {
    const int bj  = blockIdx.x;
    const int b   = bj / NC;
    const int j   = bj - b * NC;
    const int tid = threadIdx.x;
    const int C2  = C >> 1;

    const size_t rowbase = ((size_t)b * T + (size_t)j * L) * C;
    const float2* kp = (const float2*)(kg + rowbase) + tid;
    const float2* vp = (const float2*)(vg + rowbase) + tid;
    float2*       yp = (float2*)(y + rowbase) + tid;
    const float2  wc = ((const float2*)w)[tid];
    const float2  uc = ((const float2*)u)[tid];

    const int base = j * (B * C) + b * C + 2 * tid;
    float2 a2 = *(const float2*)(sa + base);
    float2 b2 = *(const float2*)(sb + base);
    float2 p2 = *(const float2*)(sp + base);
    float aa0 = a2.x, bb0 = b2.x, pp0 = p2.x;
    float aa1 = a2.y, bb1 = b2.y, pp1 = p2.y;

    float2 kb[GSZ], vb[GSZ];
    #pragma unroll
    for (int g = 0; g < GSZ; ++g) { kb[g] = kp[g * C2]; vb[g] = vp[g * C2]; }

    for (int t0 = 0; t0 < L - GSZ; t0 += GSZ) {
        float2 kn[GSZ], vn[GSZ];
        #pragma unroll
        for (int g = 0; g < GSZ; ++g) {
            kn[g] = kp[(t0 + GSZ + g) * C2];
            vn[g] = vp[(t0 + GSZ + g) * C2];
        }
        #pragma unroll
        for (int g = 0; g < GSZ; ++g) {
            float2 yo;
            yo.x = wkv_ostep(aa0, bb0, pp0, uc.x, kb[g].x, vb[g].x);
            yo.y = wkv_ostep(aa1, bb1, pp1, uc.y, kb[g].y, vb[g].y);
            yp[(t0 + g) * C2] = yo;
            wkv_step(aa0, bb0, pp0, wc.x, kb[g].x, vb[g].x);
            wkv_step(aa1, bb1, pp1, wc.y, kb[g].y, vb[g].y);
        }
        #pragma unroll
        for (int g = 0; g < GSZ; ++g) { kb[g] = kn[g]; vb[g] = vn[g]; }
    }
    const int tl = L - GSZ;
    #pragma unroll
    for (int g = 0; g < GSZ; ++g) {
        float2 yo;
        yo.x = wkv_ostep(aa0, bb0, pp0, uc.x, kb[g].x, vb[g].x);
        yo.y = wkv_ostep(aa1, bb1, pp1, uc.y, kb[g].y, vb[g].y);
        yp[(tl + g) * C2] = yo;
        wkv_step(aa0, bb0, pp0, wc.x, kb[g].x, vb[g].x);
        wkv_step(aa1, bb1, pp1, wc.y, kb[g].y, vb[g].y);
    }
}

extern "C" void kernel_launch(void* const* d_in, const int* in_sizes, int n_in,
                              void* d_out, int out_size, void* d_ws, size_t ws_size,
                              hipStream_t stream) {
    // inputs: 0=B 1=T 2=C 3=w 4=u 5=k 6=v
    const float* w = (const float*)d_in[3];
    const float* u = (const float*)d_in[4];
    const float* k = (const float*)d_in[5];
    const float* v = (const float*)d_in[6];
    float* y = (float*)d_out;

    const int C  = in_sizes[3];            // 768
    const int BT = in_sizes[5] / C;        // B*T
    const int T  = 4096;                   // fixed problem instance
    const int B  = BT / T;                 // 8

    // pick NC (power of two, L multiple of GSZ) that fits workspace
    int NC = 128;
    while (NC > 1 && ((size_t)3 * B * C * NC * sizeof(float) > ws_size ||
                      (T % NC) != 0 || ((T / NC) % GSZ) != 0))
        NC >>= 1;
    const int L = T / NC;

    const int BC    = B * C;
    const int total = BC * NC;
    float* sa = (float*)d_ws;
    float* sb = sa + total;
    float* sp = sb + total;

    const int nblk = B * NC;               // one block per (b, chunk)
    const int bthr = C / 2;                // 384 threads, 2 channels each

    wkv_chunk_state<<<nblk, bthr, 0, stream>>>(w, k, v, sa, sb, sp, B, T, C, L, NC);
    wkv_prefix<<<(BC + 255) / 256, 256, 0, stream>>>(w, sa, sb, sp, B, C, L, NC);
    wkv_out<<<nblk, bthr, 0, stream>>>(w, u, k, v, sa, sb, sp, y, B, T, C, L, NC);
}